// Round 13
// baseline (148.262 us; speedup 1.0000x reference)
//
#include <hip/hip_runtime.h>
#include <math.h>

// CRITICAL: ban FMA contraction file-wide. 1-ulp iou shifts flip near-tie
// argmaxes vs numpy's correctly-rounded ref (rounds 2-4, absmax 69).
#pragma clang fp contract(off)

// Shapes: B=64, N=100, A=8732.
// Out layout (f32 flat): [0,BA) labels | [BA,5BA) boxes | [5BA,6BA) mask
// iou_pass writes ONLY the slot array (mask region): bi | 0x8000 pos bit.
// colmax u64[B*N] at out+BA: init by prior_kernel, atomicMax'd by iou_pass,
// consumed by scatter, overwritten by encode.
// gtab (packed per-(b,n) record, 32B: box.xyzw | area | prior | pad pad):
// in d_ws if big enough, else after colmax in the boxes region.

#define AA 8732
#define NN 100
#define BB 64
#define EPS_F 1e-6f
#define OVR_FLAG 0x10000
#define POS_BIT  0x8000
// qa = inter*v_rcp(uni): rel err <= ~1.8e-7. DEFL=1-5e-7 deflation makes all
// filters rigorous one-sided bounds (HW-validated rounds 8/10/11/12).
#define DEFL 0.9999995f

__constant__ int FM_SIZE[6] = {38, 19, 10, 5, 3, 1};
__constant__ int FM_NF[6]   = {4, 6, 6, 6, 4, 4};
__constant__ int FM_OFF[6]  = {0, 5776, 7942, 8542, 8692, 8728};

__device__ __forceinline__ void geom(const float4 axy, const float4 g,
                                     float area_a, float ag,
                                     float& inter, float& uni) {
    float ltx = fmaxf(axy.x, g.x);
    float lty = fmaxf(axy.y, g.y);
    float rbx = fminf(axy.z, g.z);
    float rby = fminf(axy.w, g.w);
    float w = fmaxf(rbx - ltx, 0.0f);
    float h = fmaxf(rby - lty, 0.0f);
    inter = w * h;
    uni = area_a + ag - inter;       // uni >= max area > 0 always
}

// ---------------------------------------------------------------------------
// Prior + staging: per (b,n):
//  - prior = rcp-approx max IoU over genuine candidate anchors: center cell
//    of all 6 maps + 3x3 neighborhood on the two finest maps (~110 IoUs).
//    Deflated => SAFE lower bound of the column max (all candidates genuine).
//  - writes the packed gtab record {box, area, prior, 0, 0} (32B)
//  - initializes colmax with (prior_bits<<32 | 0): low=0 loses all ties to
//    genuine submissions (low>=1), so the real winner always lands.
// ---------------------------------------------------------------------------
__global__ void prior_kernel(const float4* __restrict__ gt_boxes,
                             const float4* __restrict__ anchors_xyxy,
                             float4* __restrict__ gtab,
                             unsigned long long* __restrict__ colmax) {
    const int b = blockIdx.x;
    const int n = threadIdx.x;
    if (n >= NN) return;
    float4 g = gt_boxes[b * NN + n];
    float ag = (g.z - g.x) * (g.w - g.y);
    float cx = (g.x + g.z) * 0.5f;
    float cy = (g.y + g.w) * 0.5f;
    float best = 0.0f;
    for (int f = 0; f < 6; f++) {
        int s = FM_SIZE[f];
        int j0 = (int)(cx * (float)s); j0 = j0 < s - 1 ? j0 : s - 1;
        int i0 = (int)(cy * (float)s); i0 = i0 < s - 1 ? i0 : s - 1;
        int rad = (f < 2) ? 1 : 0;          // 3x3 on the two finest maps
        for (int di = -rad; di <= rad; di++) {
            int i = i0 + di;
            if (i < 0 || i >= s) continue;
            for (int dj = -rad; dj <= rad; dj++) {
                int j = j0 + dj;
                if (j < 0 || j >= s) continue;
                int base = FM_OFF[f] + (i * s + j) * FM_NF[f];
                for (int k = 0; k < FM_NF[f]; k++) {
                    float4 an = anchors_xyxy[base + k];
                    float area_a = (an.z - an.x) * (an.w - an.y);
                    float inter, uni;
                    geom(an, g, area_a, ag, inter, uni);
                    best = fmaxf(best, inter * __builtin_amdgcn_rcpf(uni));
                }
            }
        }
    }
    float defl = best * DEFL;        // <= colM*(1-3.2e-7): safe lower bound
    gtab[(b * NN + n) * 2 + 0] = g;
    gtab[(b * NN + n) * 2 + 1] = make_float4(ag, defl, 0.0f, 0.0f);
    colmax[b * NN + n] = ((unsigned long long)__float_as_uint(defl)) << 32;
}

// ---------------------------------------------------------------------------
// Main-pass chunk [N0,N1): per-n data via wave-uniform loads from gtab
// (compiler emits s_load — SMEM pipe, no VALU/LDS cost); only the mutable
// scurf filter stays in LDS (broadcast ds_read_b32).
// Row: record mask vs pre-deflated running threshold rt; exact div deferred.
// Col: 1-cmp __any trigger (rare after tightened prior); on trigger, exact
// div + packed u64 butterfly ((bits<<32)|(AA-a): max iou then lowest a),
// lane 0 submits atomicMax + scurf warm-up. Clamped clone lanes carry anchor
// AA-1's genuine value — idempotent under max.
// ---------------------------------------------------------------------------
template <int N0, int N1>
__device__ __forceinline__ void passChunk(
        const float4 axy, const float area_a, const unsigned lowkey,
        const int b, const int tid,
        const float4* __restrict__ gtab,
        float* scurf,
        unsigned long long* __restrict__ colmax,
        float& rt, unsigned& rm)
{
    #pragma unroll 4
    for (int n = N0; n < N1; n++) {
        float4 g  = gtab[(b * NN + n) * 2 + 0];     // uniform -> s_load
        float  ag = gtab[(b * NN + n) * 2 + 1].x;   // uniform -> s_load
        float inter, uni;
        geom(axy, g, area_a, ag, inter, uni);
        float qa = inter * __builtin_amdgcn_rcpf(uni);
        bool r = (qa > 0.0f) && (qa >= rt);          // row near-record
        rt = fmaxf(rt, qa * DEFL);
        rm |= (r ? 1u : 0u) << (n - N0);
        float cf = scurf[n];                         // ds_read_b32 broadcast
        if (__any((int)(qa >= cf))) {                // column trigger (rare)
            float iou = inter / uni;                 // exact IEEE == numpy
            bool cc = (qa >= cf);
            unsigned long long p = cc
                ? ((((unsigned long long)__float_as_uint(iou)) << 32) |
                   (unsigned long long)lowkey) : 0ull;
            #pragma unroll
            for (int off = 32; off > 0; off >>= 1) {
                unsigned long long o = __shfl_xor(p, off);
                p = o > p ? o : p;
            }
            if ((tid & 63) == 0 && p != 0ull) {
                atomicMax(colmax + b * NN + n, p);
                atomicMax((unsigned*)&scurf[n],
                    __float_as_uint(__uint_as_float((unsigned)(p >> 32)) * DEFL));
            }
        }
    }
}

__global__ __launch_bounds__(256) void iou_pass_kernel(
        const float4* __restrict__ gtab,            // packed per-(b,n) records
        const float4* __restrict__ anchors_xyxy,    // A
        unsigned long long* __restrict__ colmax,    // B*N packed, prior-init
        int* __restrict__ out_slot)                 // -> out[5BA..6BA)
{
    const int b = blockIdx.y;
    const int tid = threadIdx.x;
    const int a = blockIdx.x * 256 + tid;
    const bool valid = (a < AA);
    const int ac = valid ? a : (AA - 1);

    __shared__ float scurf[NN];    // mutable column filter (deflated bounds)

    if (tid < NN) scurf[tid] = gtab[(b * NN + tid) * 2 + 1].y;
    __syncthreads();

    const float4 axy = anchors_xyxy[ac];
    const float area_a = (axy.z - axy.x) * (axy.w - axy.y);
    const unsigned lowkey = (unsigned)(AA - ac);    // bigger = lower anchor

    // ---------------- Phase A ----------------
    float rt = 0.0f;               // running (deflated) row-record threshold
    unsigned rm0 = 0, rm1 = 0, rm2 = 0, rm3 = 0;
    passChunk<0, 32>(axy, area_a, lowkey, b, tid, gtab, scurf, colmax, rt, rm0);
    passChunk<32, 64>(axy, area_a, lowkey, b, tid, gtab, scurf, colmax, rt, rm1);
    passChunk<64, 96>(axy, area_a, lowkey, b, tid, gtab, scurf, colmax, rt, rm2);
    passChunk<96, NN>(axy, area_a, lowkey, b, tid, gtab, scurf, colmax, rt, rm3);

    // ---------------- Phase B: row replay (ascending n = numpy order) -----
    float bv = 0.0f;   // all-zero row: bv=0, bi=0 == numpy argmax
    int bi = 0;
    unsigned rms[4] = {rm0, rm1, rm2, rm3};
    #pragma unroll
    for (int h = 0; h < 4; h++) {
        unsigned m = rms[h];
        const int nb = h * 32;
        while (m) {
            int n = __builtin_ctz(m) + nb;
            m &= m - 1;
            float4 g  = gtab[(b * NN + n) * 2 + 0];
            float  ag = gtab[(b * NN + n) * 2 + 1].x;
            float inter, uni;
            geom(axy, g, area_a, ag, inter, uni);
            float qa = inter * __builtin_amdgcn_rcpf(uni);
            if (qa > 0.0f && qa >= rt) {             // final-threshold re-test
                float iou = inter / uni;             // exact IEEE == numpy
                if (iou > bv) { bv = iou; bi = n; }  // strict >: first max
            }
        }
    }

    if (valid) {
        // pos folded into slot; override applied later (OVR_FLAG dominates).
        out_slot[(size_t)b * AA + a] = bi | (bv > 0.5f ? POS_BIT : 0);
    }
}

// ---------------------------------------------------------------------------
// Scatter gt->anchor override: np fancy-assignment last-n-wins ==
// atomicMax over (OVR_FLAG + n). low==0 (prior sentinel) rejected by guard.
// OVR_FLAG (0x10000) dominates any POS_BIT|bi (<=0x8063).
// ---------------------------------------------------------------------------
__global__ void scatter_kernel(const unsigned long long* __restrict__ colmax,
                               int* __restrict__ out_slot) {
    const int b = blockIdx.x;
    const int n = threadIdx.x;
    if (n < NN) {
        unsigned long long v = colmax[b * NN + n];
        unsigned low = (unsigned)(v & 0xFFFFFFFFull);
        if (low >= 1u && low <= (unsigned)AA) {
            int idx = AA - (int)low;
            atomicMax(&out_slot[(size_t)b * AA + idx], OVR_FLAG + n);
        }
    }
}

// ---------------------------------------------------------------------------
// Encode: decode slot (override / pos / idx), encode boxes, write all three
// outputs. Overwrites the boxes region (incl. colmax/gtab scratch bytes).
// ---------------------------------------------------------------------------
__global__ __launch_bounds__(256) void encode_kernel(
        const int* __restrict__ gt_labels,
        const float4* __restrict__ gt_boxes,        // xyxy
        const float4* __restrict__ anchors_cxcywh,
        float* __restrict__ out)
{
    const int b = blockIdx.y;
    const int tid = threadIdx.x;
    const int a = blockIdx.x * 256 + tid;

    __shared__ float4 sg[NN];
    __shared__ int    slab[NN];
    if (tid < NN) {
        sg[tid]   = gt_boxes[b * NN + tid];
        slab[tid] = gt_labels[b * NN + tid];
    }
    __syncthreads();
    if (a >= AA) return;

    const size_t BA = (size_t)BB * AA;
    const size_t base = (size_t)b * AA + a;

    int s = ((const int*)(out + 5 * BA))[base];

    int idx; bool pos;
    if (s >= OVR_FLAG) { idx = s - OVR_FLAG;  pos = true; }
    else               { idx = s & 0x7FFF;    pos = (s & POS_BIT) != 0; }

    const float4 g = sg[idx];
    const float gcx = (g.x + g.z) * 0.5f;
    const float gcy = (g.y + g.w) * 0.5f;
    const float gw  = g.z - g.x;
    const float gh  = g.w - g.y;

    const float4 anc = anchors_cxcywh[a];
    const float ecx = (gcx - anc.x) / anc.z;
    const float ecy = (gcy - anc.y) / anc.w;
    const float ew  = logf((gw + EPS_F) / (anc.z + EPS_F));
    const float eh  = logf((gh + EPS_F) / (anc.w + EPS_F));

    out[base] = pos ? (float)slab[idx] : 0.0f;                   // labels
    ((float4*)(out + BA))[base] = make_float4(ecx, ecy, ew, eh); // boxes
    out[5 * BA + base] = pos ? 1.0f : 0.0f;                      // mask
}

extern "C" void kernel_launch(void* const* d_in, const int* in_sizes, int n_in,
                              void* d_out, int out_size, void* d_ws, size_t ws_size,
                              hipStream_t stream) {
    const int*    gt_labels    = (const int*)d_in[0];
    const float4* gt_boxes     = (const float4*)d_in[1];
    const float4* anchors_cxcy = (const float4*)d_in[2];
    const float4* anchors_xyxy = (const float4*)d_in[3];
    float* out = (float*)d_out;

    const size_t BA = (size_t)BB * AA;
    unsigned long long* colmax = (unsigned long long*)(out + BA); // 32B-aligned
    int* slot = (int*)(out + 5 * BA);

    // gtab: 2 float4 per (b,n) = 204,800 B. Prefer d_ws; fall back to the
    // boxes region right after colmax (BA*4 and colmax size are 32B-aligned;
    // encode overwrites it all later). Host-side constant choice: capture-safe.
    const size_t gtab_bytes = (size_t)BB * NN * 2 * sizeof(float4);
    float4* gtab = (ws_size >= gtab_bytes)
        ? (float4*)d_ws
        : (float4*)(out + BA + (size_t)BB * NN * 2);

    prior_kernel<<<BB, 128, 0, stream>>>(gt_boxes, anchors_xyxy, gtab, colmax);

    dim3 grid((AA + 255) / 256, BB);    // (35, 64) — 1 anchor/thread
    iou_pass_kernel<<<grid, 256, 0, stream>>>(gtab, anchors_xyxy, colmax, slot);
    scatter_kernel<<<BB, 128, 0, stream>>>(colmax, slot);
    encode_kernel<<<grid, 256, 0, stream>>>(gt_labels, gt_boxes, anchors_cxcy,
                                            out);
}